// Round 21
// baseline (56.889 us; speedup 1.0000x reference)
//
#include <hip/hip_runtime.h>

typedef __attribute__((ext_vector_type(4))) int   i32x4;
typedef __attribute__((ext_vector_type(8))) int   i32x8;
typedef __attribute__((ext_vector_type(16))) float f32x16;

// ---------------------------------------------------------------------------
// f32 -> fp4 e2m1 (nearest), values {0,.5,1,1.5,2,3,4,6} with sign.
__device__ __forceinline__ unsigned enc4(float v) {
    unsigned s = (__float_as_uint(v) >> 31) << 3;
    float a = fabsf(v);
    unsigned c = a < 0.25f ? 0u : a < 0.75f ? 1u : a < 1.25f ? 2u : a < 1.75f ? 3u
               : a < 2.5f  ? 4u : a < 3.5f  ? 5u : a < 5.0f  ? 6u : 7u;
    return s | c;
}

__device__ __forceinline__ unsigned pack8(const float* p, bool valid) {
    if (!valid) return 0u;
    float4 v0 = *(const float4*)p;
    float4 v1 = *(const float4*)(p + 4);
    return enc4(v0.x) | (enc4(v0.y) << 4) | (enc4(v0.z) << 8)  | (enc4(v0.w) << 12)
         | (enc4(v1.x) << 16) | (enc4(v1.y) << 20) | (enc4(v1.z) << 24) | (enc4(v1.w) << 28);
}

// Fused slice + convert(f32 -> packed fp4 e2m1) + mask-zero, writing the
// operands PRE-TILED in GEMM LDS-slot order (r18-verified layout):
//   dword addr = panel*32768 + kt*2048 + h*1024 + row*4 + q
//   (elems of dword = kt*64 + h*32 + q*8 .. +8 of row)
// NEW (r21): one block per (operand, panel, kt). Thread t writes output
// dwords [t*8, t*8+8) -> the block's 8KB tile is written as one contiguous
// span (2x uint4 per thread) = perfectly coalesced HBM writes (old version
// scattered 16B chunks at 4KB stride -> ~4x write amplification).
// t*8+i <-> h=t>>7, row=2*(t&127)+(i>>2), q=i&3  (derivation checked).
// Even/odd row pair shares one len[b] lookup (pair never crosses batch).
__global__ void conv_kernel(const float* __restrict__ im, const int* __restrict__ iml,
                            const float* __restrict__ ss, const int* __restrict__ sl,
                            unsigned* __restrict__ Ad, unsigned* __restrict__ Bd)
{
    int bid = blockIdx.x;
    const float* src; const int* len; unsigned* dst; int rawL, adj;
    if (bid < 512) { src = im; len = iml; dst = Ad; rawL = 65; adj = -1; }
    else { bid -= 512; src = ss; len = sl; dst = Bd; rawL = 67; adj = -3; }
    const int panel = bid >> 4;
    const int kt    = bid & 15;
    const int t  = threadIdx.x;
    const int h  = t >> 7;
    const int rp = t & 127;
    const int m0 = panel * 256 + rp * 2;   // even row; odd = m0+1 (same batch)
    const int b  = m0 >> 6;
    const int i0 = m0 & 63;
    const int lim = len[b] + adj;
    const int col = kt * 64 + h * 32;

    unsigned w[8];
#pragma unroll
    for (int r = 0; r < 2; ++r) {
        const bool valid = (i0 + r) < lim;
        const float* p = src + (((size_t)(b * rawL + 1 + i0 + r)) << 10) + col;
#pragma unroll
        for (int q = 0; q < 4; ++q)
            w[r * 4 + q] = pack8(p + q * 8, valid);
    }
    unsigned* o = dst + (size_t)panel * 32768 + kt * 2048 + t * 8;
    *(uint4*)o       = make_uint4(w[0], w[1], w[2], w[3]);
    *(uint4*)(o + 4) = make_uint4(w[4], w[5], w[6], w[7]);
}

// ---------------------------------------------------------------------------
__device__ __forceinline__ void gload_lds16(const void* g, void* l) {
    __builtin_amdgcn_global_load_lds((const __attribute__((address_space(1))) void*)g,
                                     (__attribute__((address_space(3))) void*)l,
                                     16, 0, 0);
}

__device__ __forceinline__ i32x8 dup4(i32x4 a) {
    return __builtin_shufflevector(a, a, 0, 1, 2, 3, 0, 1, 2, 3);
}

// 256x256 tile, BK=64 (fp4), 8 waves (2M x 4N), per-wave 128x64.
// r20-verified GEMM, byte-identical: pre-tiled operands (0 bank conflicts,
// contiguous 8KB gload staging), 2 K-TILES PER BODY (one {vmcnt(0);
// s_barrier} per 2 k-tiles), ring-3 of 16KB slot-pairs (96 KiB).
// Body j: [gate][stage(j+2): tiles 2j+4,2j+5][read ktile 2j+1 -> setO]
//         [MFMA ktile 2j (setE)][read ktile 2j+2 -> setE][MFMA 2j+1 (setO)]
// Hazards: entry vmcnt(0) drains stage(j+1) (1 body ~3100cyc old -> free)
// covering both in-body reads; stage(j+2) overwrites pair (j-1)%3 last read
// in body j-1 (before this barrier) -> WAR-safe; MFMA(2j+1) is >=1
// MFMA-block after its reads -> lgkm covered.
// MFMA: mfma_scale_f32_32x32x64_f8f6f4, cbsz=blgp=4 (fp4), scale=1 (E8M0 127).
// C/D (r10-verified): col=lane&31, row=(reg&3)+8*(reg>>2)+4*(lane>>5).
__global__ void __launch_bounds__(512) gemm_aggr_kernel(const unsigned char* __restrict__ A,
                                                        const unsigned char* __restrict__ B,
                                                        float* __restrict__ aggr)
{
    __shared__ __align__(16) char As[3][16384];   // slot-pair: 2 tiles x 8KB
    __shared__ __align__(16) char Bs[3][16384];

    const int tid  = threadIdx.x;
    const int lane = tid & 63;
    const int wid  = tid >> 6;        // 0..7
    const int wr   = wid >> 2;        // 0..1 : 128-row half of BM=256
    const int wc   = wid & 3;         // 0..3 : 64-col quarter of BN=256
    const int tm   = blockIdx.y;      // 0..31
    const int tn   = blockIdx.x;      // 0..31

    const int r31 = lane & 31;
    const int g2  = lane >> 5;        // 0..1

    // Staging: panel base + ktile*8192 + tid*16 -- contiguous 8KB per tile.
    const unsigned char* gA_t = A + (size_t)tm * 131072 + tid * 16;
    const unsigned char* gB_t = B + (size_t)tn * 131072 + tid * 16;

    // stage body-pair j: tiles 2j, 2j+1 -> slot pair j%3 (4 gloads)
#define STAGE(j)                                                              \
    gload_lds16(gA_t + (2*(j))   * 8192, As[(j) % 3]        + tid * 16);      \
    gload_lds16(gA_t + (2*(j)+1) * 8192, As[(j) % 3] + 8192 + tid * 16);      \
    gload_lds16(gB_t + (2*(j))   * 8192, Bs[(j) % 3]        + tid * 16);      \
    gload_lds16(gB_t + (2*(j)+1) * 8192, Bs[(j) % 3] + 8192 + tid * 16);

    f32x16 acc[4][2];   // [32-row block mi][32-col block ni]
#pragma unroll
    for (int mi = 0; mi < 4; ++mi)
#pragma unroll
        for (int ni = 0; ni < 2; ++ni)
#pragma unroll
            for (int r = 0; r < 16; ++r)
                acc[mi][ni][r] = 0.f;

    // Fragment byte offsets within an 8KB tile: g2*4096 + row*16.
    const int aOff = g2 * 4096 + (wr * 128 + r31) * 16;   // + mi*512
    const int bOff = g2 * 4096 + (wc * 64 + r31) * 16;    // + ni*512

    i32x4 faE[4], fbE[2], faO[4], fbO[2];   // E = even ktiles, O = odd

#define READF(FA, FB, Ab, Bb)                                               \
    FA[0] = *(const i32x4*)((Ab) + aOff);                                   \
    FA[1] = *(const i32x4*)((Ab) + aOff + 512);                             \
    FA[2] = *(const i32x4*)((Ab) + aOff + 1024);                            \
    FA[3] = *(const i32x4*)((Ab) + aOff + 1536);                            \
    FB[0] = *(const i32x4*)((Bb) + bOff);                                   \
    FB[1] = *(const i32x4*)((Bb) + bOff + 512);

    // Prologue: stage pairs 0,1; wait pair 0; read ktile 0 -> setE.
    STAGE(0)
    STAGE(1)
    asm volatile("s_waitcnt vmcnt(4)" ::: "memory");   // pair 0 landed
    __builtin_amdgcn_s_barrier();
    __builtin_amdgcn_sched_barrier(0);
    READF(faE, fbE, As[0], Bs[0])

#define MFMA8(CA, CB)                                                       \
    __builtin_amdgcn_s_setprio(1);                                          \
    acc[0][0] = __builtin_amdgcn_mfma_scale_f32_32x32x64_f8f6f4(            \
        dup4(CA[0]), dup4(CB[0]), acc[0][0], 4, 4, 0, 127, 0, 127);         \
    acc[0][1] = __builtin_amdgcn_mfma_scale_f32_32x32x64_f8f6f4(            \
        dup4(CA[0]), dup4(CB[1]), acc[0][1], 4, 4, 0, 127, 0, 127);         \
    acc[1][0] = __builtin_amdgcn_mfma_scale_f32_32x32x64_f8f6f4(            \
        dup4(CA[1]), dup4(CB[0]), acc[1][0], 4, 4, 0, 127, 0, 127);         \
    acc[1][1] = __builtin_amdgcn_mfma_scale_f32_32x32x64_f8f6f4(            \
        dup4(CA[1]), dup4(CB[1]), acc[1][1], 4, 4, 0, 127, 0, 127);         \
    acc[2][0] = __builtin_amdgcn_mfma_scale_f32_32x32x64_f8f6f4(            \
        dup4(CA[2]), dup4(CB[0]), acc[2][0], 4, 4, 0, 127, 0, 127);         \
    acc[2][1] = __builtin_amdgcn_mfma_scale_f32_32x32x64_f8f6f4(            \
        dup4(CA[2]), dup4(CB[1]), acc[2][1], 4, 4, 0, 127, 0, 127);         \
    acc[3][0] = __builtin_amdgcn_mfma_scale_f32_32x32x64_f8f6f4(            \
        dup4(CA[3]), dup4(CB[0]), acc[3][0], 4, 4, 0, 127, 0, 127);         \
    acc[3][1] = __builtin_amdgcn_mfma_scale_f32_32x32x64_f8f6f4(            \
        dup4(CA[3]), dup4(CB[1]), acc[3][1], 4, 4, 0, 127, 0, 127);         \
    __builtin_amdgcn_s_setprio(0);

#define BODY(J)                                                             \
  {                                                                         \
    asm volatile("s_waitcnt vmcnt(0)" ::: "memory");                        \
    __builtin_amdgcn_s_barrier();                                           \
    __builtin_amdgcn_sched_barrier(0);                                      \
    if ((J) + 2 <= 7) { STAGE((J) + 2) }                                    \
    READF(faO, fbO, As[(J) % 3] + 8192, Bs[(J) % 3] + 8192)  /* kt 2J+1 */  \
    MFMA8(faE, fbE)                                          /* kt 2J   */  \
    if ((J) < 7) {                                                          \
        READF(faE, fbE, As[((J) + 1) % 3], Bs[((J) + 1) % 3]) /* 2J+2 */    \
    }                                                                       \
    MFMA8(faO, fbO)                                          /* kt 2J+1 */  \
  }

    BODY(0) BODY(1) BODY(2) BODY(3) BODY(4) BODY(5) BODY(6) BODY(7)
#undef STAGE
#undef READF
#undef MFMA8
#undef BODY

    // Fused reduction per 64x64 (b,t) cell (r10-verified layout).
    // C/D: col = lane&31, row = (reg&3) + 8*(reg>>2) + 4*(lane>>5).
#pragma unroll
    for (int h = 0; h < 2; ++h) {
        float cm[2];
#pragma unroll
        for (int ni = 0; ni < 2; ++ni) {
            float m = acc[h * 2][ni][0];
#pragma unroll
            for (int dm = 0; dm < 2; ++dm)
#pragma unroll
                for (int r = 0; r < 16; ++r)
                    m = fmaxf(m, acc[h * 2 + dm][ni][r]);
            m = fmaxf(m, __shfl_xor(m, 32));   // other 16 rows of the 32-row tile
            cm[ni] = m;                        // col max, replicated over lane>>5
        }
        float s = cm[0] + cm[1];
        s += __shfl_xor(s, 1);
        s += __shfl_xor(s, 2);
        s += __shfl_xor(s, 4);
        s += __shfl_xor(s, 8);
        s += __shfl_xor(s, 16);
        if (lane == 0) {
            int b = tm * 4 + wr * 2 + h;
            int t = tn * 4 + wc;
            aggr[b * 128 + t] = s;
        }
    }
}

// ---------------------------------------------------------------------------
// Parallel loss: stage 1 = one block per x (128 threads over y), stage 2 = sum.
__global__ void loss_stage1(const float* __restrict__ aggr, float* __restrict__ red)
{
    const int x = blockIdx.x;
    const int y = threadIdx.x;
    const float diag = aggr[x * 129];
    float ms = 0.f, mi = 0.f;
    if (y != x) {
        ms = fmaxf(0.2f + aggr[x * 128 + y] - diag, 0.f);
        mi = fmaxf(0.2f + aggr[y * 128 + x] - diag, 0.f);
    }
#pragma unroll
    for (int o = 32; o; o >>= 1) {
        ms = fmaxf(ms, __shfl_xor(ms, o));
        mi = fmaxf(mi, __shfl_xor(mi, o));
    }
    __shared__ float sm[2], si[2];
    if ((y & 63) == 0) { sm[y >> 6] = ms; si[y >> 6] = mi; }
    __syncthreads();
    if (y == 0) red[x] = fmaxf(sm[0], sm[1]) + fmaxf(si[0], si[1]);
}

__global__ void loss_stage2(const float* __restrict__ red, float* __restrict__ out)
{
    float v = red[threadIdx.x];
#pragma unroll
    for (int o = 32; o; o >>= 1) v += __shfl_xor(v, o);
    __shared__ float s[2];
    if ((threadIdx.x & 63) == 0) s[threadIdx.x >> 6] = v;
    __syncthreads();
    if (threadIdx.x == 0) *out = s[0] + s[1];
}

// ---------------------------------------------------------------------------
extern "C" void kernel_launch(void* const* d_in, const int* in_sizes, int n_in,
                              void* d_out, int out_size, void* d_ws, size_t ws_size,
                              hipStream_t stream)
{
    const float* im_set = (const float*)d_in[0];
    const float* s_seq  = (const float*)d_in[1];
    const int*   im_len = (const int*)d_in[2];
    const int*   s_len  = (const int*)d_in[3];
    float* out = (float*)d_out;

    unsigned char* Abf = (unsigned char*)d_ws;                          // 4 MiB
    unsigned char* Bbf = (unsigned char*)d_ws + (4u << 20);             // 4 MiB
    float*         agg = (float*)((char*)d_ws + (8u << 20));            // 64 KiB
    float*         red = (float*)((char*)d_ws + (8u << 20) + 65536);    // 512 B

    conv_kernel<<<1024, 256, 0, stream>>>(im_set, im_len, s_seq, s_len,
                                          (unsigned*)Abf, (unsigned*)Bbf);

    gemm_aggr_kernel<<<dim3(32, 32), 512, 0, stream>>>(Abf, Bbf, agg);

    loss_stage1<<<128, 128, 0, stream>>>(agg, red);
    loss_stage2<<<1, 128, 0, stream>>>(red, out);
}

// Round 22
// 52.994 us; speedup vs baseline: 1.0735x; 1.0735x over previous
//
#include <hip/hip_runtime.h>

typedef __attribute__((ext_vector_type(4))) int   i32x4;
typedef __attribute__((ext_vector_type(8))) int   i32x8;
typedef __attribute__((ext_vector_type(16))) float f32x16;

// ---------------------------------------------------------------------------
// f32 -> fp4 e2m1 (nearest), values {0,.5,1,1.5,2,3,4,6} with sign.
__device__ __forceinline__ unsigned enc4(float v) {
    unsigned s = (__float_as_uint(v) >> 31) << 3;
    float a = fabsf(v);
    unsigned c = a < 0.25f ? 0u : a < 0.75f ? 1u : a < 1.25f ? 2u : a < 1.75f ? 3u
               : a < 2.5f  ? 4u : a < 3.5f  ? 5u : a < 5.0f  ? 6u : 7u;
    return s | c;
}

// Fused slice + convert(f32 -> packed fp4 e2m1) + mask-zero, writing the
// operands PRE-TILED in GEMM LDS-slot order (r18/r20-verified; r21's
// coalesced-write variant regressed -- it scattered the dominant READ
// stream -- so this is the r20 version, reverted):
//   dword addr = panel(m>>8)*32768 + kt(c>>6)*2048 + h((c>>5)&1)*1024
//              + row(m&255)*4 + q((c>>3)&3)
__global__ void conv_kernel(const float* __restrict__ im, const int* __restrict__ iml,
                            const float* __restrict__ ss, const int* __restrict__ sl,
                            unsigned* __restrict__ Ad, unsigned* __restrict__ Bd)
{
    int bid = blockIdx.x;
    const float* src; const int* len; unsigned* dst; int rawL, adj;
    if (bid < 4096) { src = im; len = iml; dst = Ad; rawL = 65; adj = -1; }
    else { bid -= 4096; src = ss; len = sl; dst = Bd; rawL = 67; adj = -3; }
    int t = threadIdx.x;
    int m = bid * 2 + (t >> 7);        // output row 0..8191
    int c = (t & 127) * 8;             // elem offset within row
    int b = m >> 6;
    int i = m & 63;
    int lim = len[b] + adj;
    float4 v0 = make_float4(0.f, 0.f, 0.f, 0.f), v1 = v0;
    if (i < lim) {
        const float* p = src + ((size_t)(b * rawL + 1 + i) << 10) + c;
        v0 = *(const float4*)p;
        v1 = *(const float4*)(p + 4);
    }
    unsigned w = enc4(v0.x) | (enc4(v0.y) << 4) | (enc4(v0.z) << 8)  | (enc4(v0.w) << 12)
               | (enc4(v1.x) << 16) | (enc4(v1.y) << 20) | (enc4(v1.z) << 24) | (enc4(v1.w) << 28);
    dst[(m >> 8) * 32768 + (c >> 6) * 2048 + ((c >> 5) & 1) * 1024
        + (m & 255) * 4 + ((c >> 3) & 3)] = w;
}

// ---------------------------------------------------------------------------
__device__ __forceinline__ void gload_lds16(const void* g, void* l) {
    __builtin_amdgcn_global_load_lds((const __attribute__((address_space(1))) void*)g,
                                     (__attribute__((address_space(3))) void*)l,
                                     16, 0, 0);
}

__device__ __forceinline__ i32x8 dup4(i32x4 a) {
    return __builtin_shufflevector(a, a, 0, 1, 2, 3, 0, 1, 2, 3);
}

// 256x256 tile, BK=64 (fp4), 8 waves (2M x 4N), per-wave 128x64.
// Pre-tiled operands (r18: 0 bank conflicts, contiguous 8KB gload staging).
// NEW (r22): 4 K-TILES PER BODY -> 4 gates total (r20's gate-halving bought
// exactly the modeled ~450cyc/gate; same lever again). RING-2 double-buffer
// of 32KB quad-slots (128 KiB LDS, still 1 block/CU).
// Body j (ktiles 4j..4j+3, buffer c=j%2):
//   [gate: vmcnt(0); s_barrier][stage buffer (j+1)%2: 8 gloads]
//   [READ 4j, 4j+1][MFMA 4j][READ 4j+2][MFMA 4j+1][READ 4j+3][MFMA 4j+2]
//   [MFMA 4j+3]
// Ring-2 hazards: gate drains stage issued 1 body (~6200cyc) ago -> free;
// body j-1's reads of buffer (j+1)%2 completed before its own lgkm-gated
// MFMAs, which precede body j's entry barrier -> stage WAR-safe. All reads
// stay inside their gated body (none hoisted across the gate -- that would
// race the in-flight stage, unlike r20's ring-3).
// MFMA: mfma_scale_f32_32x32x64_f8f6f4, cbsz=blgp=4 (fp4), scale=1 (E8M0 127).
// C/D (r10-verified): col=lane&31, row=(reg&3)+8*(reg>>2)+4*(lane>>5).
__global__ void __launch_bounds__(512) gemm_aggr_kernel(const unsigned char* __restrict__ A,
                                                        const unsigned char* __restrict__ B,
                                                        float* __restrict__ aggr)
{
    __shared__ __align__(16) char As[2][32768];   // quad-slot: 4 tiles x 8KB
    __shared__ __align__(16) char Bs[2][32768];

    const int tid  = threadIdx.x;
    const int lane = tid & 63;
    const int wid  = tid >> 6;        // 0..7
    const int wr   = wid >> 2;        // 0..1 : 128-row half of BM=256
    const int wc   = wid & 3;         // 0..3 : 64-col quarter of BN=256
    const int tm   = blockIdx.y;      // 0..31
    const int tn   = blockIdx.x;      // 0..31

    const int r31 = lane & 31;
    const int g2  = lane >> 5;        // 0..1

    // Staging: panel base + ktile*8192 + tid*16 -- contiguous 8KB per tile.
    const unsigned char* gA_t = A + (size_t)tm * 131072 + tid * 16;
    const unsigned char* gB_t = B + (size_t)tn * 131072 + tid * 16;

    // stage body j's ktiles 4j..4j+3 -> buffer j%2 (8 gloads)
#define STAGE(j)                                                              \
    gload_lds16(gA_t + (4*(j))   * 8192, As[(j) & 1]         + tid * 16);     \
    gload_lds16(gA_t + (4*(j)+1) * 8192, As[(j) & 1] +  8192 + tid * 16);     \
    gload_lds16(gA_t + (4*(j)+2) * 8192, As[(j) & 1] + 16384 + tid * 16);     \
    gload_lds16(gA_t + (4*(j)+3) * 8192, As[(j) & 1] + 24576 + tid * 16);     \
    gload_lds16(gB_t + (4*(j))   * 8192, Bs[(j) & 1]         + tid * 16);     \
    gload_lds16(gB_t + (4*(j)+1) * 8192, Bs[(j) & 1] +  8192 + tid * 16);     \
    gload_lds16(gB_t + (4*(j)+2) * 8192, Bs[(j) & 1] + 16384 + tid * 16);     \
    gload_lds16(gB_t + (4*(j)+3) * 8192, Bs[(j) & 1] + 24576 + tid * 16);

    f32x16 acc[4][2];   // [32-row block mi][32-col block ni]
#pragma unroll
    for (int mi = 0; mi < 4; ++mi)
#pragma unroll
        for (int ni = 0; ni < 2; ++ni)
#pragma unroll
            for (int r = 0; r < 16; ++r)
                acc[mi][ni][r] = 0.f;

    // Fragment byte offsets within an 8KB tile: g2*4096 + row*16.
    const int aOff = g2 * 4096 + (wr * 128 + r31) * 16;   // + mi*512
    const int bOff = g2 * 4096 + (wc * 64 + r31) * 16;    // + ni*512

    i32x4 faE[4], fbE[2], faO[4], fbO[2];   // E/O fragment double-buffer

#define READF(FA, FB, Ab, Bb)                                               \
    FA[0] = *(const i32x4*)((Ab) + aOff);                                   \
    FA[1] = *(const i32x4*)((Ab) + aOff + 512);                             \
    FA[2] = *(const i32x4*)((Ab) + aOff + 1024);                            \
    FA[3] = *(const i32x4*)((Ab) + aOff + 1536);                            \
    FB[0] = *(const i32x4*)((Bb) + bOff);                                   \
    FB[1] = *(const i32x4*)((Bb) + bOff + 512);

#define MFMA8(CA, CB)                                                       \
    __builtin_amdgcn_s_setprio(1);                                          \
    acc[0][0] = __builtin_amdgcn_mfma_scale_f32_32x32x64_f8f6f4(            \
        dup4(CA[0]), dup4(CB[0]), acc[0][0], 4, 4, 0, 127, 0, 127);         \
    acc[0][1] = __builtin_amdgcn_mfma_scale_f32_32x32x64_f8f6f4(            \
        dup4(CA[0]), dup4(CB[1]), acc[0][1], 4, 4, 0, 127, 0, 127);         \
    acc[1][0] = __builtin_amdgcn_mfma_scale_f32_32x32x64_f8f6f4(            \
        dup4(CA[1]), dup4(CB[0]), acc[1][0], 4, 4, 0, 127, 0, 127);         \
    acc[1][1] = __builtin_amdgcn_mfma_scale_f32_32x32x64_f8f6f4(            \
        dup4(CA[1]), dup4(CB[1]), acc[1][1], 4, 4, 0, 127, 0, 127);         \
    acc[2][0] = __builtin_amdgcn_mfma_scale_f32_32x32x64_f8f6f4(            \
        dup4(CA[2]), dup4(CB[0]), acc[2][0], 4, 4, 0, 127, 0, 127);         \
    acc[2][1] = __builtin_amdgcn_mfma_scale_f32_32x32x64_f8f6f4(            \
        dup4(CA[2]), dup4(CB[1]), acc[2][1], 4, 4, 0, 127, 0, 127);         \
    acc[3][0] = __builtin_amdgcn_mfma_scale_f32_32x32x64_f8f6f4(            \
        dup4(CA[3]), dup4(CB[0]), acc[3][0], 4, 4, 0, 127, 0, 127);         \
    acc[3][1] = __builtin_amdgcn_mfma_scale_f32_32x32x64_f8f6f4(            \
        dup4(CA[3]), dup4(CB[1]), acc[3][1], 4, 4, 0, 127, 0, 127);         \
    __builtin_amdgcn_s_setprio(0);

#define BODY(J)                                                             \
  {                                                                         \
    const char* Ab = As[(J) & 1];                                           \
    const char* Bb = Bs[(J) & 1];                                           \
    asm volatile("s_waitcnt vmcnt(0)" ::: "memory");                        \
    __builtin_amdgcn_s_barrier();                                           \
    __builtin_amdgcn_sched_barrier(0);                                      \
    if ((J) < 3) { STAGE((J) + 1) }                                         \
    READF(faE, fbE, Ab,          Bb)            /* ktile 4J   */            \
    READF(faO, fbO, Ab +  8192,  Bb +  8192)    /* ktile 4J+1 */            \
    MFMA8(faE, fbE)                                                         \
    READF(faE, fbE, Ab + 16384,  Bb + 16384)    /* ktile 4J+2 */            \
    MFMA8(faO, fbO)                                                         \
    READF(faO, fbO, Ab + 24576,  Bb + 24576)    /* ktile 4J+3 */            \
    MFMA8(faE, fbE)                                                         \
    MFMA8(faO, fbO)                                                         \
  }

    // Prologue: stage body 0's buffer; body 0's gate drains it.
    STAGE(0)
    BODY(0) BODY(1) BODY(2) BODY(3)
#undef STAGE
#undef READF
#undef MFMA8
#undef BODY

    // Fused reduction per 64x64 (b,t) cell (r10-verified layout).
    // C/D: col = lane&31, row = (reg&3) + 8*(reg>>2) + 4*(lane>>5).
#pragma unroll
    for (int h = 0; h < 2; ++h) {
        float cm[2];
#pragma unroll
        for (int ni = 0; ni < 2; ++ni) {
            float m = acc[h * 2][ni][0];
#pragma unroll
            for (int dm = 0; dm < 2; ++dm)
#pragma unroll
                for (int r = 0; r < 16; ++r)
                    m = fmaxf(m, acc[h * 2 + dm][ni][r]);
            m = fmaxf(m, __shfl_xor(m, 32));   // other 16 rows of the 32-row tile
            cm[ni] = m;                        // col max, replicated over lane>>5
        }
        float s = cm[0] + cm[1];
        s += __shfl_xor(s, 1);
        s += __shfl_xor(s, 2);
        s += __shfl_xor(s, 4);
        s += __shfl_xor(s, 8);
        s += __shfl_xor(s, 16);
        if (lane == 0) {
            int b = tm * 4 + wr * 2 + h;
            int t = tn * 4 + wc;
            aggr[b * 128 + t] = s;
        }
    }
}

// ---------------------------------------------------------------------------
// Parallel loss: stage 1 = one block per x (128 threads over y), stage 2 = sum.
__global__ void loss_stage1(const float* __restrict__ aggr, float* __restrict__ red)
{
    const int x = blockIdx.x;
    const int y = threadIdx.x;
    const float diag = aggr[x * 129];
    float ms = 0.f, mi = 0.f;
    if (y != x) {
        ms = fmaxf(0.2f + aggr[x * 128 + y] - diag, 0.f);
        mi = fmaxf(0.2f + aggr[y * 128 + x] - diag, 0.f);
    }
#pragma unroll
    for (int o = 32; o; o >>= 1) {
        ms = fmaxf(ms, __shfl_xor(ms, o));
        mi = fmaxf(mi, __shfl_xor(mi, o));
    }
    __shared__ float sm[2], si[2];
    if ((y & 63) == 0) { sm[y >> 6] = ms; si[y >> 6] = mi; }
    __syncthreads();
    if (y == 0) red[x] = fmaxf(sm[0], sm[1]) + fmaxf(si[0], si[1]);
}

__global__ void loss_stage2(const float* __restrict__ red, float* __restrict__ out)
{
    float v = red[threadIdx.x];
#pragma unroll
    for (int o = 32; o; o >>= 1) v += __shfl_xor(v, o);
    __shared__ float s[2];
    if ((threadIdx.x & 63) == 0) s[threadIdx.x >> 6] = v;
    __syncthreads();
    if (threadIdx.x == 0) *out = s[0] + s[1];
}

// ---------------------------------------------------------------------------
extern "C" void kernel_launch(void* const* d_in, const int* in_sizes, int n_in,
                              void* d_out, int out_size, void* d_ws, size_t ws_size,
                              hipStream_t stream)
{
    const float* im_set = (const float*)d_in[0];
    const float* s_seq  = (const float*)d_in[1];
    const int*   im_len = (const int*)d_in[2];
    const int*   s_len  = (const int*)d_in[3];
    float* out = (float*)d_out;

    unsigned char* Abf = (unsigned char*)d_ws;                          // 4 MiB
    unsigned char* Bbf = (unsigned char*)d_ws + (4u << 20);             // 4 MiB
    float*         agg = (float*)((char*)d_ws + (8u << 20));            // 64 KiB
    float*         red = (float*)((char*)d_ws + (8u << 20) + 65536);    // 512 B

    conv_kernel<<<8192, 256, 0, stream>>>(im_set, im_len, s_seq, s_len,
                                          (unsigned*)Abf, (unsigned*)Bbf);

    gemm_aggr_kernel<<<dim3(32, 32), 512, 0, stream>>>(Abf, Bbf, agg);

    loss_stage1<<<128, 128, 0, stream>>>(agg, red);
    loss_stage2<<<1, 128, 0, stream>>>(red, out);
}